// Round 16
// baseline (493.258 us; speedup 1.0000x reference)
//
#include <hip/hip_runtime.h>
#include <hip/hip_bf16.h>

#define N_NODES 100000
#define N_EDGES 1600000
#define N_EL    200000
// D_IN = D_HID = 128; layer-3 output D = 64. f32 inputs, int32 indices, f32 output.
// Round 16: gather128 restructured to 4-edges-per-wave (16 lanes x dwordx4 per row,
// cross-group shfl_xor reduction). Discriminates issue-bound vs fabric-bound:
// same bytes (FETCH should stay ~190MB), 4x fewer VMEM instructions.

#define NB_SCAN ((N_NODES + 255) / 256)   // 391
#define CPAD 16                            // ints per counter line

typedef unsigned int uint32;
typedef unsigned short ushort16;
typedef __attribute__((ext_vector_type(8))) short short8;   // 8 bf16 (4 VGPRs)
typedef __attribute__((ext_vector_type(4))) float f32x4;

static __device__ __forceinline__ ushort16 f2bf(float f) {
    uint32 u = __float_as_uint(f);
    u += 0x7fffu + ((u >> 16) & 1u);      // RNE
    return (ushort16)(u >> 16);
}
static __device__ __forceinline__ float bf_lo(uint32 p) { return __uint_as_float(p << 16); }
static __device__ __forceinline__ float bf_hi(uint32 p) { return __uint_as_float(p & 0xffff0000u); }
static __device__ __forceinline__ float bf2f(ushort16 h) { return __uint_as_float((uint32)h << 16); }

// ---------------- pass 1: rank + histogram, line-padded counters ----------------
__global__ void k_rank(const int* __restrict__ dst, int* __restrict__ cpad,
                       int* __restrict__ r) {
    int e = blockIdx.x * blockDim.x + threadIdx.x;
    if (e < N_EDGES) r[e] = atomicAdd(&cpad[(size_t)dst[e] * CPAD], 1);
}

// ---------------- scan pass 1 (+ dinv); deg read from padded counters ----------------
__global__ void k_scan1(const int* __restrict__ cpad, int* __restrict__ rowptr,
                        int* __restrict__ bsum, float* __restrict__ dinv) {
    __shared__ int s[256];
    int t = threadIdx.x;
    int i = blockIdx.x * 256 + t;
    int v = (i < N_NODES) ? cpad[(size_t)i * CPAD] : 0;
    if (i < N_NODES) dinv[i] = 1.0f / sqrtf((float)(v + 1));   // +1 self-loop
    s[t] = v;
    __syncthreads();
    for (int off = 1; off < 256; off <<= 1) {
        int u = (t >= off) ? s[t - off] : 0;
        __syncthreads();
        s[t] += u;
        __syncthreads();
    }
    if (i < N_NODES) rowptr[i] = s[t] - v;          // exclusive, local
    if (t == 255) bsum[blockIdx.x] = s[255];
}

__global__ void k_scan2(const int* __restrict__ bsum, int* __restrict__ boff) {
    __shared__ int s[512];
    int t = threadIdx.x;
    int v = (t < NB_SCAN) ? bsum[t] : 0;
    s[t] = v;
    __syncthreads();
    for (int off = 1; off < 512; off <<= 1) {
        int u = (t >= off) ? s[t - off] : 0;
        __syncthreads();
        s[t] += u;
        __syncthreads();
    }
    if (t < NB_SCAN) boff[t] = s[t] - v;            // exclusive
    if (t == NB_SCAN - 1) boff[NB_SCAN] = s[t];     // total
}

__global__ void k_scan3(int* __restrict__ rowptr, const int* __restrict__ boff) {
    int i = blockIdx.x * 256 + threadIdx.x;
    if (i < N_NODES) rowptr[i] += boff[blockIdx.x];
    if (i == 0) rowptr[N_NODES] = boff[NB_SCAN];
}

// ---------------- pass 2: atomic-free CSR fill ----------------
__global__ void k_fill2(const int* __restrict__ src, const int* __restrict__ dst,
                        const int* __restrict__ rowptr, const int* __restrict__ r,
                        int* __restrict__ col) {
    int e = blockIdx.x * blockDim.x + threadIdx.x;
    if (e >= N_EDGES) return;
    int pos = rowptr[dst[e]] + r[e];
    __builtin_nontemporal_store(src[e], &col[pos]);
}

// ---------------- A-fragment loaders ----------------
static __device__ __forceinline__ short8 load_afrag(const float* arow, int off) {
    float4 a0 = *(const float4*)(arow + off);
    float4 a1 = *(const float4*)(arow + off + 4);
    short8 af;
    af[0] = (short)f2bf(a0.x); af[1] = (short)f2bf(a0.y);
    af[2] = (short)f2bf(a0.z); af[3] = (short)f2bf(a0.w);
    af[4] = (short)f2bf(a1.x); af[5] = (short)f2bf(a1.y);
    af[6] = (short)f2bf(a1.z); af[7] = (short)f2bf(a1.w);
    return af;
}
static __device__ __forceinline__ short8 load_afrag(const ushort16* arow, int off) {
    return *(const short8*)(arow + off);   // 16B aligned
}

// ---------------- MFMA GEMM: t[n,:] = bf16( dinv[n] * (A[n,:128] @ W[128,D]) ) ----
template <int D, typename AT>
__global__ __launch_bounds__(256, 4) void k_gemm_mfma(const AT* __restrict__ A,
        const float* __restrict__ W, const float* __restrict__ dinv,
        ushort16* __restrict__ C) {
    constexpr int NT = D / 16;                 // 8 (D=128) or 4 (D=64)
    __shared__ short sB[4 * NT * 64 * 8];      // 32 KB / 16 KB

    int tid = threadIdx.x;

    // stage W -> LDS in B-fragment order
    for (int idx = tid; idx < 128 * D; idx += 256) {
        int k = idx / D;
        int n = idx % D;
        int kt = k >> 5, kr = k & 31;
        int q = kr >> 3, j = kr & 7;
        int nt = n >> 4, nn = n & 15;
        sB[(((kt * NT + nt) * 64) + q * 16 + nn) * 8 + j] = (short)f2bf(W[idx]);
    }
    __syncthreads();

    int w = tid >> 6;
    int l = tid & 63;
    int q = l >> 4;
    int nn15 = l & 15;
    int m0 = blockIdx.x * 64 + w * 16;

    f32x4 acc[NT];
#pragma unroll
    for (int i = 0; i < NT; ++i) acc[i] = (f32x4){0.f, 0.f, 0.f, 0.f};

    int m = m0 + nn15;
    m = min(m, N_NODES - 1);                    // tail clamp (loads only)
    const AT* arow = A + (size_t)m * 128;

#pragma unroll
    for (int kt = 0; kt < 4; ++kt) {
        short8 af = load_afrag(arow, kt * 32 + q * 8);
#pragma unroll
        for (int nt = 0; nt < NT; ++nt) {
            short8 bf = *(const short8*)&sB[((kt * NT + nt) * 64 + l) * 8];
            acc[nt] = __builtin_amdgcn_mfma_f32_16x16x32_bf16(af, bf, acc[nt], 0, 0, 0);
        }
    }

    // epilogue: node = m0 + q*4 + r, col = nt*16 + nn15
    float4 dv = *(const float4*)(dinv + m0 + 4 * q);
    const float* dvp = (const float*)&dv;
#pragma unroll
    for (int nt = 0; nt < NT; ++nt) {
#pragma unroll
        for (int r = 0; r < 4; ++r) {
            int node = m0 + q * 4 + r;
            if (node < N_NODES) {
                float val = acc[nt][r] * dvp[r];
                C[(size_t)node * D + nt * 16 + nn15] = f2bf(val);
            }
        }
    }
}

// ---------------- gather, D=128 v2: one wave/node, 4 edges concurrent ----------------
// lane = g*16 + c: group g (0..3) handles edges j = beg+g (mod 4); lane reads
// uint4 chunk c of the 256B row (cols c*8..c*8+7). Final shfl_xor(16,32) reduce.
template <bool RELU>
__global__ void k_gather128(const int* __restrict__ rowptr, const int* __restrict__ col,
                            const float* __restrict__ dinv, const uint4* __restrict__ t,
                            const float* __restrict__ b, uint4* __restrict__ outbuf) {
    unsigned wid = (blockIdx.x * blockDim.x + threadIdx.x) >> 6;
    int lane = threadIdx.x & 63;
    int g = lane >> 4;
    int c = lane & 15;
    if (wid >= N_NODES) return;
    int beg = rowptr[wid], end = rowptr[wid + 1];

    float a0 = 0.f, a1 = 0.f, a2 = 0.f, a3 = 0.f;
    float a4 = 0.f, a5 = 0.f, a6 = 0.f, a7 = 0.f;

    // self-loop: group 0 adds t[wid]
    if (g == 0) {
        uint4 v = t[(size_t)wid * 16 + c];
        a0 += bf_lo(v.x); a1 += bf_hi(v.x); a2 += bf_lo(v.y); a3 += bf_hi(v.y);
        a4 += bf_lo(v.z); a5 += bf_hi(v.z); a6 += bf_lo(v.w); a7 += bf_hi(v.w);
    }

    int j = beg + g;
    for (; j + 4 < end; j += 8) {          // 2 edges/group in flight (8 per wave)
        int s0 = col[j];
        int s1 = col[j + 4];
        uint4 v0 = t[(size_t)s0 * 16 + c];
        uint4 v1 = t[(size_t)s1 * 16 + c];
        a0 += bf_lo(v0.x) + bf_lo(v1.x); a1 += bf_hi(v0.x) + bf_hi(v1.x);
        a2 += bf_lo(v0.y) + bf_lo(v1.y); a3 += bf_hi(v0.y) + bf_hi(v1.y);
        a4 += bf_lo(v0.z) + bf_lo(v1.z); a5 += bf_hi(v0.z) + bf_hi(v1.z);
        a6 += bf_lo(v0.w) + bf_lo(v1.w); a7 += bf_hi(v0.w) + bf_hi(v1.w);
    }
    for (; j < end; j += 4) {
        int s = col[j];
        uint4 v = t[(size_t)s * 16 + c];
        a0 += bf_lo(v.x); a1 += bf_hi(v.x); a2 += bf_lo(v.y); a3 += bf_hi(v.y);
        a4 += bf_lo(v.z); a5 += bf_hi(v.z); a6 += bf_lo(v.w); a7 += bf_hi(v.w);
    }

    // cross-group reduction (all lanes end with full sums for their c-chunk)
    a0 += __shfl_xor(a0, 16); a1 += __shfl_xor(a1, 16);
    a2 += __shfl_xor(a2, 16); a3 += __shfl_xor(a3, 16);
    a4 += __shfl_xor(a4, 16); a5 += __shfl_xor(a5, 16);
    a6 += __shfl_xor(a6, 16); a7 += __shfl_xor(a7, 16);
    a0 += __shfl_xor(a0, 32); a1 += __shfl_xor(a1, 32);
    a2 += __shfl_xor(a2, 32); a3 += __shfl_xor(a3, 32);
    a4 += __shfl_xor(a4, 32); a5 += __shfl_xor(a5, 32);
    a6 += __shfl_xor(a6, 32); a7 += __shfl_xor(a7, 32);

    if (g == 0) {
        float di = dinv[wid];
        const float4* b4 = (const float4*)b;
        float4 bb0 = b4[c * 2];
        float4 bb1 = b4[c * 2 + 1];
        float o0 = di * a0 + bb0.x, o1 = di * a1 + bb0.y;
        float o2 = di * a2 + bb0.z, o3 = di * a3 + bb0.w;
        float o4 = di * a4 + bb1.x, o5 = di * a5 + bb1.y;
        float o6 = di * a6 + bb1.z, o7 = di * a7 + bb1.w;
        if (RELU) {
            o0 = fmaxf(o0, 0.f); o1 = fmaxf(o1, 0.f);
            o2 = fmaxf(o2, 0.f); o3 = fmaxf(o3, 0.f);
            o4 = fmaxf(o4, 0.f); o5 = fmaxf(o5, 0.f);
            o6 = fmaxf(o6, 0.f); o7 = fmaxf(o7, 0.f);
        }
        uint4 pk;
        pk.x = (uint32)f2bf(o0) | ((uint32)f2bf(o1) << 16);
        pk.y = (uint32)f2bf(o2) | ((uint32)f2bf(o3) << 16);
        pk.z = (uint32)f2bf(o4) | ((uint32)f2bf(o5) << 16);
        pk.w = (uint32)f2bf(o6) | ((uint32)f2bf(o7) << 16);
        outbuf[(size_t)wid * 16 + c] = pk;
    }
}

// ---------------- gather, D=64: bf16 out (unchanged) ----------------
template <bool RELU>
__global__ void k_gather64(const int* __restrict__ rowptr, const int* __restrict__ col,
                           const float* __restrict__ dinv, const ushort16* __restrict__ t,
                           const float* __restrict__ b, ushort16* __restrict__ outbuf) {
    unsigned wid = (blockIdx.x * blockDim.x + threadIdx.x) >> 6;
    int lane = threadIdx.x & 63;
    if (wid >= N_NODES) return;
    int beg = rowptr[wid], end = rowptr[wid + 1];
    float acc = bf2f(t[(size_t)wid * 64 + lane]);
    int j = beg;
    for (; j + 8 <= end; j += 8) {
        int s0 = col[j], s1 = col[j+1], s2 = col[j+2], s3 = col[j+3];
        int s4 = col[j+4], s5 = col[j+5], s6 = col[j+6], s7 = col[j+7];
        float v0 = bf2f(t[(size_t)s0 * 64 + lane]);
        float v1 = bf2f(t[(size_t)s1 * 64 + lane]);
        float v2 = bf2f(t[(size_t)s2 * 64 + lane]);
        float v3 = bf2f(t[(size_t)s3 * 64 + lane]);
        float v4 = bf2f(t[(size_t)s4 * 64 + lane]);
        float v5 = bf2f(t[(size_t)s5 * 64 + lane]);
        float v6 = bf2f(t[(size_t)s6 * 64 + lane]);
        float v7 = bf2f(t[(size_t)s7 * 64 + lane]);
        acc += (v0 + v1) + (v2 + v3) + ((v4 + v5) + (v6 + v7));
    }
    for (; j + 4 <= end; j += 4) {
        int s0 = col[j], s1 = col[j+1], s2 = col[j+2], s3 = col[j+3];
        acc += (bf2f(t[(size_t)s0 * 64 + lane]) + bf2f(t[(size_t)s1 * 64 + lane]))
             + (bf2f(t[(size_t)s2 * 64 + lane]) + bf2f(t[(size_t)s3 * 64 + lane]));
    }
    for (; j < end; ++j) acc += bf2f(t[(size_t)col[j] * 64 + lane]);
    float o = dinv[wid] * acc + b[lane];
    if (RELU) o = fmaxf(o, 0.f);
    outbuf[(size_t)wid * 64 + lane] = f2bf(o);
}

// ---------------- decode: z is bf16 [N x 64] ----------------
__global__ void k_decode(const int* __restrict__ eli, const ushort16* __restrict__ z,
                         float* __restrict__ out) {
    int e = blockIdx.x * blockDim.x + threadIdx.x;
    if (e >= N_EL) return;
    int a = eli[e];
    int b = eli[N_EL + e];
    const uint4* za = (const uint4*)(z + (size_t)a * 64);
    const uint4* zb = (const uint4*)(z + (size_t)b * 64);
    float acc = 0.0f;
#pragma unroll
    for (int i = 0; i < 8; ++i) {
        uint4 va = za[i], vb = zb[i];
        acc += bf_lo(va.x) * bf_lo(vb.x) + bf_hi(va.x) * bf_hi(vb.x);
        acc += bf_lo(va.y) * bf_lo(vb.y) + bf_hi(va.y) * bf_hi(vb.y);
        acc += bf_lo(va.z) * bf_lo(vb.z) + bf_hi(va.z) * bf_hi(vb.z);
        acc += bf_lo(va.w) * bf_lo(vb.w) + bf_hi(va.w) * bf_hi(vb.w);
    }
    out[e] = acc;
}

extern "C" void kernel_launch(void* const* d_in, const int* in_sizes, int n_in,
                              void* d_out, int out_size, void* d_ws, size_t ws_size,
                              hipStream_t stream) {
    const float* x   = (const float*)d_in[0];
    const int*   ei  = (const int*)d_in[1];
    const int*   eli = (const int*)d_in[2];
    const float* W1  = (const float*)d_in[3];
    const float* b1  = (const float*)d_in[4];
    const float* W2  = (const float*)d_in[5];
    const float* b2  = (const float*)d_in[6];
    const float* W3  = (const float*)d_in[7];
    const float* b3  = (const float*)d_in[8];
    float* out = (float*)d_out;

    const int* srcA = ei;
    const int* dstA = ei + N_EDGES;

    // workspace layout (bytes) — non-overlapping (verified round 15):
    char* ws = (char*)d_ws;
    float*    dinv   = (float*)   (ws + 0);
    int*      rowptr = (int*)     (ws + (1024u << 10));
    int*      bsum   = (int*)     (ws + (1888u << 10));
    int*      boff   = (int*)     (ws + (1896u << 10));
    int*      col    = (int*)     (ws + (2048u << 10));
    int*      r      = (int*)     (ws + (9u << 20));
    ushort16* t      = (ushort16*)(ws + (16u << 20));
    ushort16* aggb   = (ushort16*)(ws + (48u << 20));
    int*      cpad   = (int*)     (ws + (80u << 20));

    const int B = 256;
    const int gE  = (N_EDGES + B - 1) / B;
    const int gG  = (N_NODES * 64 + B - 1) / B;
    const int gT  = (N_NODES + 63) / 64;      // 1563
    const int gEL = (N_EL + B - 1) / B;

    // ---- CSR build (single atomic pass, padded counters) ----
    hipMemsetAsync(cpad, 0, (size_t)N_NODES * CPAD * sizeof(int), stream);
    k_rank<<<gE, B, 0, stream>>>(dstA, cpad, r);
    k_scan1<<<NB_SCAN, 256, 0, stream>>>(cpad, rowptr, bsum, dinv);
    k_scan2<<<1, 512, 0, stream>>>(bsum, boff);
    k_scan3<<<NB_SCAN, 256, 0, stream>>>(rowptr, boff);
    k_fill2<<<gE, B, 0, stream>>>(srcA, dstA, rowptr, r, col);

    // ---- layer 1 (A = x, f32) ----
    k_gemm_mfma<128, float><<<gT, B, 0, stream>>>(x, W1, dinv, t);
    k_gather128<true><<<gG, B, 0, stream>>>(rowptr, col, dinv, (const uint4*)t, b1,
                                            (uint4*)aggb);
    // ---- layer 2 (A = h1, bf16) ----
    k_gemm_mfma<128, ushort16><<<gT, B, 0, stream>>>(aggb, W2, dinv, t);
    k_gather128<true><<<gG, B, 0, stream>>>(rowptr, col, dinv, (const uint4*)t, b2,
                                            (uint4*)aggb);
    // ---- layer 3 (A = h2, bf16) ----
    k_gemm_mfma<64, ushort16><<<gT, B, 0, stream>>>(aggb, W3, dinv, t);
    k_gather64<false><<<gG, B, 0, stream>>>(rowptr, col, dinv, t, b3, aggb);

    // ---- decode ----
    k_decode<<<gEL, B, 0, stream>>>(eli, aggb, out);
}